// Round 6
// baseline (72.801 us; speedup 1.0000x reference)
//
#include <hip/hip_runtime.h>
#include <math.h>

// SoftAvULoss: N x C (524288 x 100) f32 logits, int32 labels -> scalar loss.
// 4 lanes per row, 16 rows per wave; row quarter in registers (6 float4 + 1
// scalar issued up front), local (m, S=sum e^{x-m}, W=sum e^{x-m}(x-m)),
// 2-step shfl_xor flash-merge -> row stats.
// accurate <=> logits[row][label] == rowmax (exact, ties measure-zero).
//
// R4: no atomics for the 4 sums (8192 same-address atomicAdds pinned ~139us).
// R5: grid 2048 regressed slightly -> back to 1024 (occupancy not binding).
// R6: fuse the final reduction via last-block-done: block stores its float4
//     partial, agent-scope acq_rel fetch_add on a counter; last block reduces
//     1024 slots + writes loss. Removes the second kernel launch (~6-8us of
//     graph-node drain + dispatch). Counter zeroed by hipMemsetAsync per call.

#define C_COLS 100
#define GRID_MAIN 1024

__global__ __launch_bounds__(256) void avu_fused(const float* __restrict__ logits,
                                                 const int* __restrict__ labels,
                                                 float4* __restrict__ partials,
                                                 unsigned int* __restrict__ counter,
                                                 float* __restrict__ out,
                                                 int ntiles) {
    const int tid  = threadIdx.x;
    const int lane = tid & 63;
    const int wid  = tid >> 6;       // wave in block (0..3)
    const int s    = lane & 3;       // sublane within row group
    const int rsub = lane >> 2;      // row within wave (0..15)

    float s_ac = 0.f, s_au = 0.f, s_ic = 0.f, s_iu = 0.f;

    for (int tile = blockIdx.x; tile < ntiles; tile += gridDim.x) {
        const int row = tile * 64 + wid * 16 + rsub;
        const float* base = logits + (size_t)row * C_COLS;

        // ---- issue all row-quarter loads up front (deep MLP)
        const float* p = base + 4 * s;
        const float4 v0 = *(const float4*)(p +  0);
        const float4 v1 = *(const float4*)(p + 16);
        const float4 v2 = *(const float4*)(p + 32);
        const float4 v3 = *(const float4*)(p + 48);
        const float4 v4 = *(const float4*)(p + 64);
        const float  tl = base[96 + s];
        const float4 v5 = *(const float4*)(p + 80);

        // dependent pair (16 active lanes), consumed only at the tile end
        float xl = 0.f;
        if (s == 0) { xl = base[labels[row]]; }

        // ---- local max over 25 elems
        float m = fmaxf(fmaxf(fmaxf(v0.x, v0.y), fmaxf(v0.z, v0.w)),
                  fmaxf(fmaxf(fmaxf(v1.x, v1.y), fmaxf(v1.z, v1.w)),
                  fmaxf(fmaxf(fmaxf(v2.x, v2.y), fmaxf(v2.z, v2.w)),
                  fmaxf(fmaxf(fmaxf(v3.x, v3.y), fmaxf(v3.z, v3.w)),
                  fmaxf(fmaxf(fmaxf(v4.x, v4.y), fmaxf(v4.z, v4.w)),
                  fmaxf(fmaxf(fmaxf(v5.x, v5.y), fmaxf(v5.z, v5.w)), tl))))));

        // ---- local S, W
        float S = 0.f, W = 0.f;
        {
            const float4 vv[6] = {v0, v1, v2, v3, v4, v5};
            #pragma unroll
            for (int k = 0; k < 6; ++k) {
                const float d0 = vv[k].x - m, d1 = vv[k].y - m;
                const float d2 = vv[k].z - m, d3 = vv[k].w - m;
                const float e0 = __expf(d0), e1 = __expf(d1);
                const float e2 = __expf(d2), e3 = __expf(d3);
                S += (e0 + e1) + (e2 + e3);
                W += (e0 * d0 + e1 * d1) + (e2 * d2 + e3 * d3);
            }
            const float dt = tl - m;
            const float et = __expf(dt);
            S += et; W += et * dt;
        }

        // ---- merge (m,S,W) across the 4 sublanes
        #pragma unroll
        for (int d = 1; d <= 2; d <<= 1) {
            const float mo = __shfl_xor(m, d);
            const float So = __shfl_xor(S, d);
            const float Wo = __shfl_xor(W, d);
            const float mn = fmaxf(m, mo);
            const float da = m - mn, db = mo - mn;
            const float ea = __expf(da), eb = __expf(db);
            const float Wn = ea * (W + da * S) + eb * (Wo + db * So);
            S = ea * S + eb * So;
            W = Wn;
            m = mn;
        }

        // ---- per-row scalars
        const float H  = __logf(S) - W / S;          // entropy
        const float en = H * (1.0f / C_COLS);
        const float z  = 100.0f * (__logf(en) - __logf(1.0f - en)); // K=0.5, TEMP=0.01
        const float su = (z >= 0.f) ? 1.0f / (1.0f + __expf(-z))
                                    : __expf(z) / (1.0f + __expf(z));
        const float e2h = __expf(2.0f * H);
        const float th  = (e2h - 1.0f) / (e2h + 1.0f);  // tanh(H)
        const float omt = 2.0f / (e2h + 1.0f);          // 1 - tanh(H)

        const float cterm = (1.0f - su) * omt;
        const float uterm = su * th;

        if (s == 0) {
            if (xl == m) { s_ac += cterm; s_au += uterm; }
            else         { s_ic += cterm; s_iu += uterm; }
        }
    }

    // ---- wave reduction of the 4 partials
    #pragma unroll
    for (int off = 32; off > 0; off >>= 1) {
        s_ac += __shfl_xor(s_ac, off);
        s_au += __shfl_xor(s_au, off);
        s_ic += __shfl_xor(s_ic, off);
        s_iu += __shfl_xor(s_iu, off);
    }

    // ---- cross-wave reduction, one plain store per block, last-block-done
    __shared__ float red[4][4];
    __shared__ int last_flag;
    if ((tid & 63) == 0) {
        red[wid][0] = s_ac; red[wid][1] = s_au;
        red[wid][2] = s_ic; red[wid][3] = s_iu;
    }
    __syncthreads();
    if (tid == 0) {
        partials[blockIdx.x] = make_float4(
            red[0][0] + red[1][0] + red[2][0] + red[3][0],
            red[0][1] + red[1][1] + red[2][1] + red[3][1],
            red[0][2] + red[1][2] + red[2][2] + red[3][2],
            red[0][3] + red[1][3] + red[2][3] + red[3][3]);
        // acq_rel, agent scope: releases our store; the winner's acquire
        // synchronizes with every prior release in the RMW sequence.
        const unsigned int prev = __hip_atomic_fetch_add(
            counter, 1u, __ATOMIC_ACQ_REL, __HIP_MEMORY_SCOPE_AGENT);
        last_flag = (prev == (unsigned int)(gridDim.x - 1)) ? 1 : 0;
    }
    __syncthreads();  // propagates tid0's acquire to the whole block

    if (last_flag) {
        float4 a = make_float4(0.f, 0.f, 0.f, 0.f);
        #pragma unroll
        for (int k = 0; k < GRID_MAIN / 256; ++k) {
            const float4 v = partials[tid + 256 * k];
            a.x += v.x; a.y += v.y; a.z += v.z; a.w += v.w;
        }
        #pragma unroll
        for (int off = 32; off > 0; off >>= 1) {
            a.x += __shfl_xor(a.x, off);
            a.y += __shfl_xor(a.y, off);
            a.z += __shfl_xor(a.z, off);
            a.w += __shfl_xor(a.w, off);
        }
        __shared__ float4 red2[4];
        if ((tid & 63) == 0) red2[tid >> 6] = a;
        __syncthreads();
        if (tid == 0) {
            const float ac = red2[0].x + red2[1].x + red2[2].x + red2[3].x;
            const float au = red2[0].y + red2[1].y + red2[2].y + red2[3].y;
            const float ic = red2[0].z + red2[1].z + red2[2].z + red2[3].z;
            const float iu = red2[0].w + red2[1].w + red2[2].w + red2[3].w;
            const float avu = (ac + iu) / (ac + au + ic + iu + 1e-10f);
            out[0] = -logf(avu + 1e-10f);
        }
    }
}

extern "C" void kernel_launch(void* const* d_in, const int* in_sizes, int n_in,
                              void* d_out, int out_size, void* d_ws, size_t ws_size,
                              hipStream_t stream) {
    const float* logits = (const float*)d_in[0];
    const int*   labels = (const int*)d_in[1];
    float* out = (float*)d_out;

    float4*       partials = (float4*)d_ws;                       // 16 KB
    unsigned int* counter  = (unsigned int*)((char*)d_ws + GRID_MAIN * sizeof(float4));

    const int nrows  = in_sizes[1];          // 524288
    const int ntiles = nrows / 64;           // 8192 (exact)

    hipMemsetAsync(counter, 0, sizeof(unsigned int), stream);
    avu_fused<<<GRID_MAIN, 256, 0, stream>>>(logits, labels, partials, counter,
                                             out, ntiles);
}

// Round 7
// 44.265 us; speedup vs baseline: 1.6447x; 1.6447x over previous
//
#include <hip/hip_runtime.h>
#include <math.h>

// SoftAvULoss: N x C (524288 x 100) f32 logits, int32 labels -> scalar loss.
// 4 lanes per row, 16 rows per wave; row quarter in registers (6 float4 + 1
// scalar issued up front), local (m, S=sum e^{x-m}, W=sum e^{x-m}(x-m)),
// 2-step shfl_xor flash-merge -> row stats.
// accurate <=> logits[row][label] == rowmax (exact, ties measure-zero).
//
// R4: no atomics for the 4 sums (same-address atomicAdd chain pinned ~139us).
// R6: ACQ_REL agent fusion regressed (+33us): per-block buffer_wbl2/inv
//     thrashed XCD L2s under the streaming reads.
// R7: fused last-block-done with ZERO cache maintenance: relaxed agent-scope
//     atomic store/load/RMW only (coherence-point accesses, no inv/wb).
//     Ordering by hand: stores -> compiler fence -> s_waitcnt(0) -> rmw.
//     Counter is a __device__ global (zero at load); winner resets it to 0
//     after reducing (safe: graph nodes on one stream serialize replays).
//     No memset node, single kernel dispatch.

#define C_COLS 100
#define GRID_MAIN 1024

__device__ unsigned int g_counter = 0;

__device__ __forceinline__ unsigned long long pack2f(float a, float b) {
    return ((unsigned long long)__float_as_uint(b) << 32) |
           (unsigned long long)__float_as_uint(a);
}

__global__ __launch_bounds__(256) void avu_fused(const float* __restrict__ logits,
                                                 const int* __restrict__ labels,
                                                 unsigned long long* __restrict__ partials,
                                                 float* __restrict__ out,
                                                 int ntiles) {
    const int tid  = threadIdx.x;
    const int lane = tid & 63;
    const int wid  = tid >> 6;       // wave in block (0..3)
    const int s    = lane & 3;       // sublane within row group
    const int rsub = lane >> 2;      // row within wave (0..15)

    float s_ac = 0.f, s_au = 0.f, s_ic = 0.f, s_iu = 0.f;

    for (int tile = blockIdx.x; tile < ntiles; tile += gridDim.x) {
        const int row = tile * 64 + wid * 16 + rsub;
        const float* base = logits + (size_t)row * C_COLS;

        // ---- issue all row-quarter loads up front (deep MLP) — exact R4 order
        const float* p = base + 4 * s;
        const float4 v0 = *(const float4*)(p +  0);
        const float4 v1 = *(const float4*)(p + 16);
        const float4 v2 = *(const float4*)(p + 32);
        const float4 v3 = *(const float4*)(p + 48);
        const float4 v4 = *(const float4*)(p + 64);
        const float  tl = base[96 + s];
        const float4 v5 = *(const float4*)(p + 80);

        // dependent pair (16 active lanes), consumed only at the tile end
        float xl = 0.f;
        if (s == 0) { xl = base[labels[row]]; }

        // ---- local max over 25 elems
        float m = fmaxf(fmaxf(fmaxf(v0.x, v0.y), fmaxf(v0.z, v0.w)),
                  fmaxf(fmaxf(fmaxf(v1.x, v1.y), fmaxf(v1.z, v1.w)),
                  fmaxf(fmaxf(fmaxf(v2.x, v2.y), fmaxf(v2.z, v2.w)),
                  fmaxf(fmaxf(fmaxf(v3.x, v3.y), fmaxf(v3.z, v3.w)),
                  fmaxf(fmaxf(fmaxf(v4.x, v4.y), fmaxf(v4.z, v4.w)),
                  fmaxf(fmaxf(fmaxf(v5.x, v5.y), fmaxf(v5.z, v5.w)), tl))))));

        // ---- local S, W
        float S = 0.f, W = 0.f;
        {
            const float4 vv[6] = {v0, v1, v2, v3, v4, v5};
            #pragma unroll
            for (int k = 0; k < 6; ++k) {
                const float d0 = vv[k].x - m, d1 = vv[k].y - m;
                const float d2 = vv[k].z - m, d3 = vv[k].w - m;
                const float e0 = __expf(d0), e1 = __expf(d1);
                const float e2 = __expf(d2), e3 = __expf(d3);
                S += (e0 + e1) + (e2 + e3);
                W += (e0 * d0 + e1 * d1) + (e2 * d2 + e3 * d3);
            }
            const float dt = tl - m;
            const float et = __expf(dt);
            S += et; W += et * dt;
        }

        // ---- merge (m,S,W) across the 4 sublanes
        #pragma unroll
        for (int d = 1; d <= 2; d <<= 1) {
            const float mo = __shfl_xor(m, d);
            const float So = __shfl_xor(S, d);
            const float Wo = __shfl_xor(W, d);
            const float mn = fmaxf(m, mo);
            const float da = m - mn, db = mo - mn;
            const float ea = __expf(da), eb = __expf(db);
            const float Wn = ea * (W + da * S) + eb * (Wo + db * So);
            S = ea * S + eb * So;
            W = Wn;
            m = mn;
        }

        // ---- per-row scalars
        const float H  = __logf(S) - W / S;          // entropy
        const float en = H * (1.0f / C_COLS);
        const float z  = 100.0f * (__logf(en) - __logf(1.0f - en)); // K=0.5, TEMP=0.01
        const float su = (z >= 0.f) ? 1.0f / (1.0f + __expf(-z))
                                    : __expf(z) / (1.0f + __expf(z));
        const float e2h = __expf(2.0f * H);
        const float th  = (e2h - 1.0f) / (e2h + 1.0f);  // tanh(H)
        const float omt = 2.0f / (e2h + 1.0f);          // 1 - tanh(H)

        const float cterm = (1.0f - su) * omt;
        const float uterm = su * th;

        if (s == 0) {
            if (xl == m) { s_ac += cterm; s_au += uterm; }
            else         { s_ic += cterm; s_iu += uterm; }
        }
    }

    // ---- wave reduction of the 4 partials
    #pragma unroll
    for (int off = 32; off > 0; off >>= 1) {
        s_ac += __shfl_xor(s_ac, off);
        s_au += __shfl_xor(s_au, off);
        s_ic += __shfl_xor(s_ic, off);
        s_iu += __shfl_xor(s_iu, off);
    }

    // ---- cross-wave reduction, relaxed coherence-point epilogue
    __shared__ float red[4][4];
    __shared__ int last_flag;
    if ((tid & 63) == 0) {
        red[wid][0] = s_ac; red[wid][1] = s_au;
        red[wid][2] = s_ic; red[wid][3] = s_iu;
    }
    __syncthreads();
    if (tid == 0) {
        const float ac = red[0][0] + red[1][0] + red[2][0] + red[3][0];
        const float au = red[0][1] + red[1][1] + red[2][1] + red[3][1];
        const float ic = red[0][2] + red[1][2] + red[2][2] + red[3][2];
        const float iu = red[0][3] + red[1][3] + red[2][3] + red[3][3];
        // relaxed agent-scope stores: go to the coherence point, NO cache
        // maintenance (the R6 killer was acq_rel's buffer_wbl2/buffer_inv).
        __hip_atomic_store(&partials[2 * blockIdx.x + 0], pack2f(ac, au),
                           __ATOMIC_RELAXED, __HIP_MEMORY_SCOPE_AGENT);
        __hip_atomic_store(&partials[2 * blockIdx.x + 1], pack2f(ic, iu),
                           __ATOMIC_RELAXED, __HIP_MEMORY_SCOPE_AGENT);
        __atomic_signal_fence(__ATOMIC_SEQ_CST);   // no compile-time reorder
        __builtin_amdgcn_s_waitcnt(0);             // stores reached coherence pt
        const unsigned int prev = __hip_atomic_fetch_add(
            &g_counter, 1u, __ATOMIC_RELAXED, __HIP_MEMORY_SCOPE_AGENT);
        last_flag = (prev == (unsigned int)(GRID_MAIN - 1)) ? 1 : 0;
    }
    __syncthreads();

    if (last_flag) {
        // winner is truly last: all 2048 slots are at the coherence point.
        // Read them with relaxed agent loads (bypass possibly-stale L1/L2).
        __atomic_signal_fence(__ATOMIC_SEQ_CST);
        float ac = 0.f, au = 0.f, ic = 0.f, iu = 0.f;
        #pragma unroll
        for (int k = 0; k < 4; ++k) {               // 4 slots per thread
            const int slot = tid * 4 + k;
            const unsigned long long a = __hip_atomic_load(
                &partials[2 * slot + 0], __ATOMIC_RELAXED, __HIP_MEMORY_SCOPE_AGENT);
            const unsigned long long b = __hip_atomic_load(
                &partials[2 * slot + 1], __ATOMIC_RELAXED, __HIP_MEMORY_SCOPE_AGENT);
            ac += __uint_as_float((unsigned int)(a & 0xffffffffull));
            au += __uint_as_float((unsigned int)(a >> 32));
            ic += __uint_as_float((unsigned int)(b & 0xffffffffull));
            iu += __uint_as_float((unsigned int)(b >> 32));
        }
        #pragma unroll
        for (int off = 32; off > 0; off >>= 1) {
            ac += __shfl_xor(ac, off);
            au += __shfl_xor(au, off);
            ic += __shfl_xor(ic, off);
            iu += __shfl_xor(iu, off);
        }
        __shared__ float red2[4][4];
        if ((tid & 63) == 0) {
            red2[tid >> 6][0] = ac; red2[tid >> 6][1] = au;
            red2[tid >> 6][2] = ic; red2[tid >> 6][3] = iu;
        }
        __syncthreads();
        if (tid == 0) {
            const float Ac = red2[0][0] + red2[1][0] + red2[2][0] + red2[3][0];
            const float Au = red2[0][1] + red2[1][1] + red2[2][1] + red2[3][1];
            const float Ic = red2[0][2] + red2[1][2] + red2[2][2] + red2[3][2];
            const float Iu = red2[0][3] + red2[1][3] + red2[2][3] + red2[3][3];
            const float avu = (Ac + Iu) / (Ac + Au + Ic + Iu + 1e-10f);
            out[0] = -logf(avu + 1e-10f);
            // reset for the next call; replays are stream-serialized so no race
            __hip_atomic_store(&g_counter, 0u,
                               __ATOMIC_RELAXED, __HIP_MEMORY_SCOPE_AGENT);
        }
    }
}

extern "C" void kernel_launch(void* const* d_in, const int* in_sizes, int n_in,
                              void* d_out, int out_size, void* d_ws, size_t ws_size,
                              hipStream_t stream) {
    const float* logits = (const float*)d_in[0];
    const int*   labels = (const int*)d_in[1];
    float* out = (float*)d_out;
    unsigned long long* partials = (unsigned long long*)d_ws;  // 2048 * 8 B

    const int nrows  = in_sizes[1];          // 524288
    const int ntiles = nrows / 64;           // 8192 (exact)

    avu_fused<<<GRID_MAIN, 256, 0, stream>>>(logits, labels, partials, out, ntiles);
}

// Round 8
// 39.580 us; speedup vs baseline: 1.8393x; 1.1184x over previous
//
#include <hip/hip_runtime.h>
#include <math.h>

// SoftAvULoss: N x C (524288 x 100) f32 logits, int32 labels -> scalar loss.
// 4 lanes per row, 16 rows per wave; row quarter held in registers (6 float4
// + 1 scalar issued up front), local (m, S=sum e^{x-m}, W=sum e^{x-m}(x-m)),
// 2-step shfl_xor flash-merge -> row stats.
// accurate <=> logits[row][label] == rowmax (exact, ties measure-zero).
//
// History:
//  R1-R3: ~139us regardless of body — pinned by 8192 same-address atomicAdds.
//  R4: per-block plain float4 partial store + tiny second kernel -> 39.75us.
//  R5: grid 2048 (occupancy 100%) -> 41.7us. Occupancy not binding; revert.
//  R6: fused last-block-done, ACQ_REL agent -> 72.8us (buffer_wbl2/inv per
//      block thrashed XCD L2s under the streaming reads).
//  R7: fused, relaxed coherence-point epilogue -> 44.3us. Still worse than
//      the graph-node boundary it replaces. Fusion abandoned.
//  R8: exact R4 revert — empirical best. Main kernel runs at ~6.2 TB/s
//      effective (~88% of the 7.1 TB/s the harness's own fills achieve);
//      traffic is minimal (each byte read once); epilogue alternatives all
//      measured slower. This is the memory-path roofline.

#define C_COLS 100
#define GRID_MAIN 1024

__global__ __launch_bounds__(256) void avu_main(const float* __restrict__ logits,
                                                const int* __restrict__ labels,
                                                float4* __restrict__ partials,
                                                int ntiles) {
    const int tid  = threadIdx.x;
    const int lane = tid & 63;
    const int wid  = tid >> 6;       // wave in block (0..3)
    const int s    = lane & 3;       // sublane within row group
    const int rsub = lane >> 2;      // row within wave (0..15)

    float s_ac = 0.f, s_au = 0.f, s_ic = 0.f, s_iu = 0.f;

    for (int tile = blockIdx.x; tile < ntiles; tile += gridDim.x) {
        const int row = tile * 64 + wid * 16 + rsub;
        const float* base = logits + (size_t)row * C_COLS;

        // scattered per-row pair (16 active lanes), consumed only at tile end
        float xl = 0.f;
        if (s == 0) { xl = base[labels[row]]; }

        // ---- issue all row-quarter loads up front
        const float* p = base + 4 * s;
        const float4 v0 = *(const float4*)(p +  0);
        const float4 v1 = *(const float4*)(p + 16);
        const float4 v2 = *(const float4*)(p + 32);
        const float4 v3 = *(const float4*)(p + 48);
        const float4 v4 = *(const float4*)(p + 64);
        const float  tl = base[96 + s];
        const float4 v5 = *(const float4*)(p + 80);

        // ---- local max over 25 elems
        float m = fmaxf(fmaxf(fmaxf(v0.x, v0.y), fmaxf(v0.z, v0.w)),
                  fmaxf(fmaxf(fmaxf(v1.x, v1.y), fmaxf(v1.z, v1.w)),
                  fmaxf(fmaxf(fmaxf(v2.x, v2.y), fmaxf(v2.z, v2.w)),
                  fmaxf(fmaxf(fmaxf(v3.x, v3.y), fmaxf(v3.z, v3.w)),
                  fmaxf(fmaxf(fmaxf(v4.x, v4.y), fmaxf(v4.z, v4.w)),
                  fmaxf(fmaxf(fmaxf(v5.x, v5.y), fmaxf(v5.z, v5.w)), tl))))));

        // ---- local S = sum e^{x-m}, W = sum e^{x-m}(x-m)
        float S = 0.f, W = 0.f;
        {
            const float4 vv[6] = {v0, v1, v2, v3, v4, v5};
            #pragma unroll
            for (int k = 0; k < 6; ++k) {
                const float d0 = vv[k].x - m, d1 = vv[k].y - m;
                const float d2 = vv[k].z - m, d3 = vv[k].w - m;
                const float e0 = __expf(d0), e1 = __expf(d1);
                const float e2 = __expf(d2), e3 = __expf(d3);
                S += (e0 + e1) + (e2 + e3);
                W += (e0 * d0 + e1 * d1) + (e2 * d2 + e3 * d3);
            }
            const float dt = tl - m;
            const float et = __expf(dt);
            S += et; W += et * dt;
        }

        // ---- merge (m,S,W) across the 4 sublanes
        #pragma unroll
        for (int d = 1; d <= 2; d <<= 1) {
            const float mo = __shfl_xor(m, d);
            const float So = __shfl_xor(S, d);
            const float Wo = __shfl_xor(W, d);
            const float mn = fmaxf(m, mo);
            const float da = m - mn, db = mo - mn;
            const float ea = __expf(da), eb = __expf(db);
            const float Wn = ea * (W + da * S) + eb * (Wo + db * So);
            S = ea * S + eb * So;
            W = Wn;
            m = mn;
        }

        // ---- per-row scalars
        const float H  = __logf(S) - W / S;          // entropy
        const float en = H * (1.0f / C_COLS);
        const float z  = 100.0f * (__logf(en) - __logf(1.0f - en)); // K=0.5, TEMP=0.01
        const float su = (z >= 0.f) ? 1.0f / (1.0f + __expf(-z))
                                    : __expf(z) / (1.0f + __expf(z));
        const float e2h = __expf(2.0f * H);
        const float th  = (e2h - 1.0f) / (e2h + 1.0f);  // tanh(H)
        const float omt = 2.0f / (e2h + 1.0f);          // 1 - tanh(H)

        const float cterm = (1.0f - su) * omt;
        const float uterm = su * th;

        if (s == 0) {
            if (xl == m) { s_ac += cterm; s_au += uterm; }
            else         { s_ic += cterm; s_iu += uterm; }
        }
    }

    // ---- wave reduction of the 4 partials
    #pragma unroll
    for (int off = 32; off > 0; off >>= 1) {
        s_ac += __shfl_xor(s_ac, off);
        s_au += __shfl_xor(s_au, off);
        s_ic += __shfl_xor(s_ic, off);
        s_iu += __shfl_xor(s_iu, off);
    }

    // ---- cross-wave reduction (4 waves/block), then ONE plain store per block
    __shared__ float red[4][4];
    if ((tid & 63) == 0) {
        red[wid][0] = s_ac; red[wid][1] = s_au;
        red[wid][2] = s_ic; red[wid][3] = s_iu;
    }
    __syncthreads();
    if (tid == 0) {
        partials[blockIdx.x] = make_float4(
            red[0][0] + red[1][0] + red[2][0] + red[3][0],
            red[0][1] + red[1][1] + red[2][1] + red[3][1],
            red[0][2] + red[1][2] + red[2][2] + red[3][2],
            red[0][3] + red[1][3] + red[2][3] + red[3][3]);
    }
}

__global__ __launch_bounds__(256) void avu_final(const float4* __restrict__ partials,
                                                 float* __restrict__ out) {
    const int tid = threadIdx.x;
    float4 a = make_float4(0.f, 0.f, 0.f, 0.f);
    #pragma unroll
    for (int k = 0; k < GRID_MAIN / 256; ++k) {
        const float4 v = partials[tid + 256 * k];
        a.x += v.x; a.y += v.y; a.z += v.z; a.w += v.w;
    }
    #pragma unroll
    for (int off = 32; off > 0; off >>= 1) {
        a.x += __shfl_xor(a.x, off);
        a.y += __shfl_xor(a.y, off);
        a.z += __shfl_xor(a.z, off);
        a.w += __shfl_xor(a.w, off);
    }
    __shared__ float4 red[4];
    if ((tid & 63) == 0) red[tid >> 6] = a;
    __syncthreads();
    if (tid == 0) {
        const float ac = red[0].x + red[1].x + red[2].x + red[3].x;
        const float au = red[0].y + red[1].y + red[2].y + red[3].y;
        const float ic = red[0].z + red[1].z + red[2].z + red[3].z;
        const float iu = red[0].w + red[1].w + red[2].w + red[3].w;
        const float avu = (ac + iu) / (ac + au + ic + iu + 1e-10f);
        out[0] = -logf(avu + 1e-10f);
    }
}

extern "C" void kernel_launch(void* const* d_in, const int* in_sizes, int n_in,
                              void* d_out, int out_size, void* d_ws, size_t ws_size,
                              hipStream_t stream) {
    const float* logits = (const float*)d_in[0];
    const int*   labels = (const int*)d_in[1];
    float*  out      = (float*)d_out;
    float4* partials = (float4*)d_ws;        // 1024 * 16 B = 16 KB

    const int nrows  = in_sizes[1];          // 524288
    const int ntiles = nrows / 64;           // 8192 (exact)

    avu_main<<<GRID_MAIN, 256, 0, stream>>>(logits, labels, partials, ntiles);
    avu_final<<<1, 256, 0, stream>>>(partials, out);
}